// Round 1
// baseline (395.807 us; speedup 1.0000x reference)
//
#include <hip/hip_runtime.h>

#define NB 2
#define NL 2048
#define NH 16
#define ND 64
// out: [B,H,L,S] f32, S = NL

// ---------------- Kernel 1: per-head projection, f64 accumulate -> f32 store
// y[b,l,h,e] = sum_d x[b,l,h,d] * W[h,d,e]
__global__ __launch_bounds__(256) void proj_kernel(const float* __restrict__ x,
                                                   const float* __restrict__ W,
                                                   float* __restrict__ y) {
    __shared__ float xrow[NH * ND];  // 1024 floats = one (b,l) slice
    const int bl = blockIdx.x;       // 0 .. NB*NL-1
    const int t = threadIdx.x;       // 0..255
    const float* xp = x + (size_t)bl * (NH * ND);
    ((float4*)xrow)[t] = ((const float4*)xp)[t];  // 256*4 = 1024
    __syncthreads();
    const int e = t & 63;
    const int hq = t >> 6;  // 0..3 ; one head per wave
    for (int h = hq; h < NH; h += 4) {
        const float* Wp = W + (size_t)h * ND * ND + e;
        const float* xh = xrow + h * ND;
        double acc = 0.0;
#pragma unroll 8
        for (int d = 0; d < ND; ++d) {
            acc += (double)xh[d] * (double)Wp[(size_t)d * ND];
        }
        y[(size_t)bl * (NH * ND) + h * ND + e] = (float)acc;
    }
}

// ---------------- Kernel 2: K_sum[b,h,e] = sum_s kf[b,s,h,e]  (f64, fixed order)
__global__ __launch_bounds__(1024) void ksum_kernel(const float* __restrict__ kf,
                                                    double* __restrict__ ksum) {
    __shared__ double part[16][64];
    const int bh = blockIdx.x;  // 0..31
    const int b = bh >> 4, h = bh & 15;
    const int t = threadIdx.x;  // 0..1023
    const int e = t & 63, c = t >> 6;  // 16 chunks of 128 keys
    const float* base = kf + ((size_t)b * NL * NH + h) * ND + e;
    double acc = 0.0;
    for (int s = c * 128; s < (c + 1) * 128; ++s)
        acc += (double)base[(size_t)s * (NH * ND)];
    part[c][e] = acc;
    __syncthreads();
    if (t < 64) {
        double s = 0.0;
#pragma unroll
        for (int c2 = 0; c2 < 16; ++c2) s += part[c2][e];
        ksum[(size_t)bh * ND + e] = s;
    }
}

// ---------------- Kernel 3: inv_den[b,h,l] = 1 / sum_e qf[b,l,h,e]*Ksum[b,h,e] (f64)
__global__ __launch_bounds__(256) void den_kernel(const float* __restrict__ qf,
                                                  const double* __restrict__ ksum,
                                                  float* __restrict__ invden) {
    __shared__ double ks[64];
    const int bh = blockIdx.x;  // 0..31
    const int b = bh >> 4, h = bh & 15;
    const int t = threadIdx.x;
    if (t < 64) ks[t] = ksum[(size_t)bh * ND + t];
    __syncthreads();
    const int l = blockIdx.y * 256 + t;
    const float* qp = qf + ((size_t)(b * NL + l) * NH + h) * ND;
    double acc = 0.0;
#pragma unroll 8
    for (int e = 0; e < ND; ++e) acc += (double)qp[e] * ks[e];
    invden[(size_t)bh * NL + l] = (float)(1.0 / acc);
}

// ---------------- Kernel 4: attn[b,h,l,s] = (q_l . k_s) * inv_den[b,h,l]
// 64x64 tile per block, 256 threads, 4x4 accum per thread, f32.
__global__ __launch_bounds__(256) void attn_kernel(const float* __restrict__ qf,
                                                   const float* __restrict__ kf,
                                                   const float* __restrict__ invden,
                                                   float* __restrict__ out) {
    __shared__ float qt[64][68];  // [e][l], padded stride 68 (16B-aligned, bank-safe)
    __shared__ float kt[64][68];  // [e][s]
    const int bh = blockIdx.z;  // 0..31 == b*16+h
    const int b = bh >> 4, h = bh & 15;
    const int l0 = blockIdx.y * 64, s0 = blockIdx.x * 64;
    const int t = threadIdx.x;
    const int row = t >> 4;    // 0..15
    const int col4 = t & 15;   // e-quad 0..15

    // Stage tiles (transposed into [e][l] / [e][s])
#pragma unroll
    for (int i = 0; i < 4; ++i) {
        const int r = row + i * 16;  // 0..63
        const float4 qv = *(const float4*)(qf + ((size_t)(b * NL + l0 + r) * NH + h) * ND + col4 * 4);
        qt[col4 * 4 + 0][r] = qv.x;
        qt[col4 * 4 + 1][r] = qv.y;
        qt[col4 * 4 + 2][r] = qv.z;
        qt[col4 * 4 + 3][r] = qv.w;
        const float4 kv = *(const float4*)(kf + ((size_t)(b * NL + s0 + r) * NH + h) * ND + col4 * 4);
        kt[col4 * 4 + 0][r] = kv.x;
        kt[col4 * 4 + 1][r] = kv.y;
        kt[col4 * 4 + 2][r] = kv.z;
        kt[col4 * 4 + 3][r] = kv.w;
    }
    __syncthreads();

    const int tl = t >> 4;   // l-quad 0..15
    const int ts = t & 15;   // s-quad 0..15
    float acc[4][4] = {};
#pragma unroll 4
    for (int e = 0; e < 64; ++e) {
        const float4 qv = *(const float4*)&qt[e][tl * 4];
        const float4 kv = *(const float4*)&kt[e][ts * 4];
        acc[0][0] += qv.x * kv.x; acc[0][1] += qv.x * kv.y; acc[0][2] += qv.x * kv.z; acc[0][3] += qv.x * kv.w;
        acc[1][0] += qv.y * kv.x; acc[1][1] += qv.y * kv.y; acc[1][2] += qv.y * kv.z; acc[1][3] += qv.y * kv.w;
        acc[2][0] += qv.z * kv.x; acc[2][1] += qv.z * kv.y; acc[2][2] += qv.z * kv.z; acc[2][3] += qv.z * kv.w;
        acc[3][0] += qv.w * kv.x; acc[3][1] += qv.w * kv.y; acc[3][2] += qv.w * kv.z; acc[3][3] += qv.w * kv.w;
    }

#pragma unroll
    for (int i = 0; i < 4; ++i) {
        const int l = l0 + tl * 4 + i;
        const float inv = invden[(size_t)bh * NL + l];
        float4 r;
        r.x = acc[i][0] * inv;
        r.y = acc[i][1] * inv;
        r.z = acc[i][2] * inv;
        r.w = acc[i][3] * inv;
        *(float4*)(out + ((size_t)bh * NL + l) * NL + s0 + ts * 4) = r;
    }
}

extern "C" void kernel_launch(void* const* d_in, const int* in_sizes, int n_in,
                              void* d_out, int out_size, void* d_ws, size_t ws_size,
                              hipStream_t stream) {
    const float* query = (const float*)d_in[0];  // [B,L,H,D]
    const float* key   = (const float*)d_in[1];  // [B,L,H,D]
    const float* Wq    = (const float*)d_in[2];  // [H,D,D]
    const float* Wk    = (const float*)d_in[3];  // [H,D,D]
    float* out = (float*)d_out;                  // [B,H,L,S]

    const size_t nqk = (size_t)NB * NL * NH * ND;  // 4194304
    float* qf = (float*)d_ws;
    float* kf = qf + nqk;
    double* ksum = (double*)(kf + nqk);            // byte offset 33554432, 8-aligned
    float* invden = (float*)(ksum + (size_t)NB * NH * ND);

    // 1) projections (f64 accumulate)
    proj_kernel<<<NB * NL, 256, 0, stream>>>(query, Wq, qf);
    proj_kernel<<<NB * NL, 256, 0, stream>>>(key, Wk, kf);

    // 2) K_sum per (b,h) in f64
    ksum_kernel<<<NB * NH, 1024, 0, stream>>>(kf, ksum);

    // 3) exact-ish denominators -> 1/den (f32 storage is pure-rounding-safe)
    den_kernel<<<dim3(NB * NH, NL / 256), 256, 0, stream>>>(qf, ksum, invden);

    // 4) the big batched GEMM + per-row scale
    attn_kernel<<<dim3(NL / 64, NL / 64, NB * NH), 256, 0, stream>>>(qf, kf, invden, out);
}

// Round 2
// 252.738 us; speedup vs baseline: 1.5661x; 1.5661x over previous
//
#include <hip/hip_runtime.h>

#define NB 2
#define NL 2048
#define NH 16
#define ND 64
// out: [B,H,L,S] f32, S = NL

typedef __attribute__((ext_vector_type(8))) short short8;
typedef __attribute__((ext_vector_type(4))) float f32x4;

// ---------------- Kernel 1: per-head projection, f64 accumulate -> f32 store
__global__ __launch_bounds__(256) void proj_kernel(const float* __restrict__ x,
                                                   const float* __restrict__ W,
                                                   float* __restrict__ y) {
    __shared__ float xrow[NH * ND];
    const int bl = blockIdx.x;
    const int t = threadIdx.x;
    const float* xp = x + (size_t)bl * (NH * ND);
    ((float4*)xrow)[t] = ((const float4*)xp)[t];
    __syncthreads();
    const int e = t & 63;
    const int hq = t >> 6;
    for (int h = hq; h < NH; h += 4) {
        const float* Wp = W + (size_t)h * ND * ND + e;
        const float* xh = xrow + h * ND;
        double acc = 0.0;
#pragma unroll 8
        for (int d = 0; d < ND; ++d) {
            acc += (double)xh[d] * (double)Wp[(size_t)d * ND];
        }
        y[(size_t)bl * (NH * ND) + h * ND + e] = (float)acc;
    }
}

// ---------------- Kernel 2: K_sum[b,h,e] = sum_s kf[b,s,h,e]  (f64, fixed order)
__global__ __launch_bounds__(1024) void ksum_kernel(const float* __restrict__ kf,
                                                    double* __restrict__ ksum) {
    __shared__ double part[16][64];
    const int bh = blockIdx.x;
    const int b = bh >> 4, h = bh & 15;
    const int t = threadIdx.x;
    const int e = t & 63, c = t >> 6;
    const float* base = kf + ((size_t)b * NL * NH + h) * ND + e;
    double acc = 0.0;
    for (int s = c * 128; s < (c + 1) * 128; ++s)
        acc += (double)base[(size_t)s * (NH * ND)];
    part[c][e] = acc;
    __syncthreads();
    if (t < 64) {
        double s = 0.0;
#pragma unroll
        for (int c2 = 0; c2 < 16; ++c2) s += part[c2][e];
        ksum[(size_t)bh * ND + e] = s;
    }
}

// ---------------- Kernel 3: inv_den[b,h,l] = 1 / (qf . Ksum)  (f64)
__global__ __launch_bounds__(256) void den_kernel(const float* __restrict__ qf,
                                                  const double* __restrict__ ksum,
                                                  float* __restrict__ invden) {
    __shared__ double ks[64];
    const int bh = blockIdx.x;
    const int b = bh >> 4, h = bh & 15;
    const int t = threadIdx.x;
    if (t < 64) ks[t] = ksum[(size_t)bh * ND + t];
    __syncthreads();
    const int l = blockIdx.y * 256 + t;
    const float* qp = qf + ((size_t)(b * NL + l) * NH + h) * ND;
    double acc = 0.0;
#pragma unroll 8
    for (int e = 0; e < ND; ++e) acc += (double)qp[e] * ks[e];
    invden[(size_t)bh * NL + l] = (float)(1.0 / acc);
}

// ---------------- Kernel 4: attn = (q . k^T) * inv_den, MFMA bf16 3-term split
// 128x128 out tile, 256 threads (4 waves, 2x2), full K=64 staged once.
__device__ __forceinline__ unsigned short f2bf_rne(float x) {
    union { float f; unsigned int u; } v; v.f = x;
    unsigned int r = v.u + 0x7fffu + ((v.u >> 16) & 1u);
    return (unsigned short)(r >> 16);
}
__device__ __forceinline__ float bf2f(unsigned short b) {
    union { unsigned int u; float f; } v; v.u = ((unsigned int)b) << 16;
    return v.f;
}

__global__ __launch_bounds__(256) void attn_kernel(const float* __restrict__ qf,
                                                   const float* __restrict__ kf,
                                                   const float* __restrict__ invden,
                                                   float* __restrict__ out) {
    // padded stride 72 (=+16B): uniform bank coverage for ds_read_b128 frags
    __shared__ unsigned short qh[128][72], ql[128][72], kh[128][72], kl[128][72];
    __shared__ float invd[128];
    const int bh = blockIdx.z;
    const int b = bh >> 4, h = bh & 15;
    const int l0 = blockIdx.y * 128, s0 = blockIdx.x * 128;
    const int t = threadIdx.x;

    // ---- stage: load f32 q/k rows, split to bf16 hi/lo in LDS
    {
        const int e4 = (t & 15) * 4;   // e offset (float4)
        const int r0 = t >> 4;         // 0..15
#pragma unroll
        for (int i = 0; i < 8; ++i) {
            const int r = r0 + i * 16;  // 0..127
            const float4 qv = *(const float4*)(qf + ((size_t)(b * NL + l0 + r) * NH + h) * ND + e4);
            const float4 kv = *(const float4*)(kf + ((size_t)(b * NL + s0 + r) * NH + h) * ND + e4);
            const float qa[4] = {qv.x, qv.y, qv.z, qv.w};
            const float ka[4] = {kv.x, kv.y, kv.z, kv.w};
#pragma unroll
            for (int j = 0; j < 4; ++j) {
                unsigned short hq_ = f2bf_rne(qa[j]);
                qh[r][e4 + j] = hq_;
                ql[r][e4 + j] = f2bf_rne(qa[j] - bf2f(hq_));
                unsigned short hk_ = f2bf_rne(ka[j]);
                kh[r][e4 + j] = hk_;
                kl[r][e4 + j] = f2bf_rne(ka[j] - bf2f(hk_));
            }
        }
        if (t < 128) invd[t] = invden[(size_t)bh * NL + l0 + t];
    }
    __syncthreads();

    // ---- compute: per wave a 64x64 quadrant = 4x4 fragments of 16x16
    const int wid = t >> 6, ln = t & 63;
    const int wr = wid >> 1, wc = wid & 1;
    const int fr = ln & 15;            // A row / B col within fragment
    const int ko = (ln >> 4) * 8;      // k base within 32-chunk

    f32x4 acc[4][4];
#pragma unroll
    for (int i = 0; i < 4; ++i)
#pragma unroll
        for (int j = 0; j < 4; ++j) acc[i][j] = (f32x4){0.f, 0.f, 0.f, 0.f};

#pragma unroll
    for (int kc = 0; kc < 2; ++kc) {
        const int e0 = kc * 32 + ko;
        short8 ah[4], al[4], bhf[4], blf[4];
#pragma unroll
        for (int i = 0; i < 4; ++i) {
            ah[i]  = *(const short8*)&qh[wr * 64 + i * 16 + fr][e0];
            al[i]  = *(const short8*)&ql[wr * 64 + i * 16 + fr][e0];
            bhf[i] = *(const short8*)&kh[wc * 64 + i * 16 + fr][e0];
            blf[i] = *(const short8*)&kl[wc * 64 + i * 16 + fr][e0];
        }
#pragma unroll
        for (int i = 0; i < 4; ++i)
#pragma unroll
            for (int j = 0; j < 4; ++j) {
                acc[i][j] = __builtin_amdgcn_mfma_f32_16x16x32_bf16(ah[i], bhf[j], acc[i][j], 0, 0, 0);
                acc[i][j] = __builtin_amdgcn_mfma_f32_16x16x32_bf16(ah[i], blf[j], acc[i][j], 0, 0, 0);
                acc[i][j] = __builtin_amdgcn_mfma_f32_16x16x32_bf16(al[i], bhf[j], acc[i][j], 0, 0, 0);
            }
    }

    // ---- epilogue: scale by inv_den, store. C/D: col=lane&15, row=(lane>>4)*4+reg
    const int crow = (ln >> 4) * 4;
#pragma unroll
    for (int i = 0; i < 4; ++i) {
#pragma unroll
        for (int r = 0; r < 4; ++r) {
            const int lrow = wr * 64 + i * 16 + crow + r;
            const float inv = invd[lrow];
            float* op = out + ((size_t)(bh * NL + l0 + lrow)) * NL + s0 + wc * 64 + fr;
#pragma unroll
            for (int j = 0; j < 4; ++j)
                op[j * 16] = acc[i][j][r] * inv;
        }
    }
}

extern "C" void kernel_launch(void* const* d_in, const int* in_sizes, int n_in,
                              void* d_out, int out_size, void* d_ws, size_t ws_size,
                              hipStream_t stream) {
    const float* query = (const float*)d_in[0];
    const float* key   = (const float*)d_in[1];
    const float* Wq    = (const float*)d_in[2];
    const float* Wk    = (const float*)d_in[3];
    float* out = (float*)d_out;

    const size_t nqk = (size_t)NB * NL * NH * ND;
    float* qf = (float*)d_ws;
    float* kf = qf + nqk;
    double* ksum = (double*)(kf + nqk);
    float* invden = (float*)(ksum + (size_t)NB * NH * ND);

    proj_kernel<<<NB * NL, 256, 0, stream>>>(query, Wq, qf);
    proj_kernel<<<NB * NL, 256, 0, stream>>>(key, Wk, kf);
    ksum_kernel<<<NB * NH, 1024, 0, stream>>>(kf, ksum);
    den_kernel<<<dim3(NB * NH, NL / 256), 256, 0, stream>>>(qf, ksum, invden);
    attn_kernel<<<dim3(NL / 128, NL / 128, NB * NH), 256, 0, stream>>>(qf, kf, invden, out);
}

// Round 4
// 193.087 us; speedup vs baseline: 2.0499x; 1.3089x over previous
//
#include <hip/hip_runtime.h>
#include <stdint.h>

#define NB 2
#define NL 2048
#define NH 16
#define ND 64
// out: [B,H,L,S] f32, S = NL

typedef __attribute__((ext_vector_type(8))) short short8;
typedef __attribute__((ext_vector_type(4))) float f32x4;
typedef __attribute__((ext_vector_type(4))) unsigned short ushort4v;

__device__ __forceinline__ unsigned short f2bf_rne(float x) {
    union { float f; unsigned int u; } v; v.f = x;
    unsigned int r = v.u + 0x7fffu + ((v.u >> 16) & 1u);
    return (unsigned short)(r >> 16);
}
__device__ __forceinline__ float bf2f(unsigned short b) {
    union { unsigned int u; float f; } v; v.u = ((unsigned int)b) << 16;
    return v.f;
}

// ---------------- Kernel A: proj + bf16 hi/lo split, head-major swizzled panels
// y[l,e] = sum_d x[b,l,h,d] * W[h,d,e]  (f32 accum — numerator-only path)
// panel store: element e of row l goes to index  e ^ ((l&7)<<3)   (byte ^ ((l&7)<<4))
__global__ __launch_bounds__(256) void proj_bf16_kernel(const float* __restrict__ x,
                                                        const float* __restrict__ W,
                                                        unsigned short* __restrict__ ph,
                                                        unsigned short* __restrict__ pl) {
    __shared__ float Wlds[ND * ND];   // [d][e]
    __shared__ float xs[128 * 68];    // [r][d], stride 68 floats
    const int blk = blockIdx.x;       // b*256 + h*16 + lc
    const int lc = blk & 15;
    const int h = (blk >> 4) & 15;
    const int b = blk >> 8;
    const int l0 = lc * 128;
    const int t = threadIdx.x;

    {
        const float4* src = (const float4*)(W + (size_t)h * ND * ND);
#pragma unroll
        for (int i = 0; i < 4; ++i)
            ((float4*)Wlds)[t + 256 * i] = src[t + 256 * i];
    }
    {
#pragma unroll
        for (int i = 0; i < 8; ++i) {
            const int idx = t + 256 * i;  // 0..2047
            const int r = idx >> 4, c = idx & 15;
            const float4 v = *(const float4*)(x + (((size_t)b * NL + l0 + r) * NH + h) * ND + c * 4);
            *(float4*)&xs[r * 68 + c * 4] = v;
        }
    }
    __syncthreads();

    const int e4 = (t & 15) * 4;
    const int rg = t >> 4;  // 0..15
    float acc[8][4] = {};
    for (int d = 0; d < ND; ++d) {
        const float4 w4 = *(const float4*)&Wlds[d * ND + e4];
#pragma unroll
        for (int it = 0; it < 8; ++it) {
            const float xv = xs[(rg + it * 16) * 68 + d];
            acc[it][0] += xv * w4.x; acc[it][1] += xv * w4.y;
            acc[it][2] += xv * w4.z; acc[it][3] += xv * w4.w;
        }
    }

    unsigned short* phh = ph + ((size_t)(b * NH + h) * NL + l0) * ND;
    unsigned short* pll = pl + ((size_t)(b * NH + h) * NL + l0) * ND;
#pragma unroll
    for (int it = 0; it < 8; ++it) {
        const int r = rg + it * 16;
        const int ep = e4 ^ ((r & 7) << 3);  // swizzled element position (8B-group safe)
        ushort4v hv, lv;
#pragma unroll
        for (int j = 0; j < 4; ++j) {
            const unsigned short hb = f2bf_rne(acc[it][j]);
            hv[j] = hb;
            lv[j] = f2bf_rne(acc[it][j] - bf2f(hb));
        }
        *(ushort4v*)&phh[(size_t)r * ND + ep] = hv;
        *(ushort4v*)&pll[(size_t)r * ND + ep] = lv;
    }
}

// ---------------- Kernel B: xsumk[b,h,e] = sum_s key[b,s,h,e]  (f64, fixed order)
__global__ __launch_bounds__(1024) void xsum_kernel(const float* __restrict__ key,
                                                    double* __restrict__ xsumk) {
    __shared__ double part[16][64];
    const int bh = blockIdx.x;
    const int b = bh >> 4, h = bh & 15;
    const int t = threadIdx.x;
    const int e = t & 63, c = t >> 6;
    const float* base = key + ((size_t)b * NL * NH + h) * ND + e;
    double acc = 0.0;
    for (int s = c * 128; s < (c + 1) * 128; ++s)
        acc += (double)base[(size_t)s * (NH * ND)];
    part[c][e] = acc;
    __syncthreads();
    if (t < 64) {
        double s2 = 0.0;
#pragma unroll
        for (int c2 = 0; c2 < 16; ++c2) s2 += part[c2][e];
        xsumk[(size_t)bh * ND + e] = s2;
    }
}

// ---------------- Kernel C: v[b,h,d] = Wq . (Wk^T . xsumk)  (f64)
__global__ __launch_bounds__(64) void prep_kernel(const double* __restrict__ xsumk,
                                                  const float* __restrict__ Wq,
                                                  const float* __restrict__ Wk,
                                                  double* __restrict__ v) {
    __shared__ double xs[ND], ks[ND];
    const int bh = blockIdx.x;
    const int h = bh & 15;
    const int t = threadIdx.x;  // 0..63
    xs[t] = xsumk[(size_t)bh * ND + t];
    __syncthreads();
    {
        double acc = 0.0;
        const float* wk = Wk + (size_t)h * ND * ND + t;  // column t
        for (int d = 0; d < ND; ++d) acc += xs[d] * (double)wk[(size_t)d * ND];
        ks[t] = acc;
    }
    __syncthreads();
    {
        double acc = 0.0;
        const float* wq = Wq + (size_t)h * ND * ND + (size_t)t * ND;  // row t
        for (int e = 0; e < ND; ++e) acc += (double)wq[e] * ks[e];
        v[(size_t)bh * ND + t] = acc;
    }
}

// ---------------- Kernel D: invden[b,h,l] = 1 / (x_q . v)  (f64 exact)
__global__ __launch_bounds__(256) void den_kernel(const float* __restrict__ xq,
                                                  const double* __restrict__ v,
                                                  float* __restrict__ invden) {
    __shared__ double vs[ND];
    const int bh = blockIdx.x;
    const int b = bh >> 4, h = bh & 15;
    const int t = threadIdx.x;
    if (t < 64) vs[t] = v[(size_t)bh * ND + t];
    __syncthreads();
    const int l = blockIdx.y * 256 + t;
    const float* xp = xq + (((size_t)b * NL + l) * NH + h) * ND;
    double acc = 0.0;
#pragma unroll 8
    for (int d = 0; d < ND; ++d) acc += (double)xp[d] * vs[d];
    invden[(size_t)bh * NL + l] = (float)(1.0 / acc);
}

// ---------------- Kernel E: attn = (q.k^T) * inv_den — MFMA, gload_lds, swizzled LDS
// 128x128 tile, 4 waves (2x2). Swapped operands: A=k-frag (rows s), B=q-frag (cols l)
// -> C/D reg index runs along s -> float4 stores.
__global__ __launch_bounds__(256) void attn_kernel(const unsigned short* __restrict__ qbh,
                                                   const unsigned short* __restrict__ qbl,
                                                   const unsigned short* __restrict__ kbh,
                                                   const unsigned short* __restrict__ kbl,
                                                   const float* __restrict__ invden,
                                                   float* __restrict__ out) {
    __shared__ unsigned short smem[4 * 128 * 64];  // qh|ql|kh|kl, 16KB each, linear
    const int bh = blockIdx.z;
    const int l0 = blockIdx.y * 128, s0 = blockIdx.x * 128;
    const int t = threadIdx.x;
    const int w = t >> 6, ln = t & 63;

    // ---- stage 64KB via global_load_lds.
    // One inst = 64 lanes * 16B = 1KB. Each wave stages its 4KB quarter of each
    // of the 4 panels: 4 arrays * 4 insts = 16 insts/wave, 64 total = 64KB.
    {
        const size_t pan = (size_t)bh * NL * ND;
        const unsigned short* srcs[4] = {qbh + pan + (size_t)l0 * ND,
                                         qbl + pan + (size_t)l0 * ND,
                                         kbh + pan + (size_t)s0 * ND,
                                         kbl + pan + (size_t)s0 * ND};
#pragma unroll
        for (int arr = 0; arr < 4; ++arr) {
            const unsigned short* s = srcs[arr] + w * 2048 + ln * 8;  // wave quarter
            unsigned short* d = smem + arr * 8192 + w * 2048;         // +lane*16B by HW
#pragma unroll
            for (int u = 0; u < 4; ++u) {
                __builtin_amdgcn_global_load_lds((const __attribute__((address_space(1))) unsigned int*)(s + u * 512),
                                                 (__attribute__((address_space(3))) unsigned int*)(d + u * 512),
                                                 16, 0, 0);
            }
        }
    }
    __syncthreads();

    const int wr = w >> 1, wc = w & 1;
    const int fr = ln & 15, g = ln >> 4;
    const int swz = (fr & 7) << 4;

    f32x4 acc[4][4];
#pragma unroll
    for (int i = 0; i < 4; ++i)
#pragma unroll
        for (int j = 0; j < 4; ++j) acc[i][j] = (f32x4){0.f, 0.f, 0.f, 0.f};

    const char* sb = (const char*)smem;
#pragma unroll
    for (int kc = 0; kc < 2; ++kc) {
        const int cofs = ((kc << 6) | (g << 4)) ^ swz;
        short8 kh_f[4], kl_f[4], qh_f[4], ql_f[4];
#pragma unroll
        for (int i = 0; i < 4; ++i) {
            const int arow = wr * 64 + i * 16 + fr;  // s rows
            kh_f[i] = *(const short8*)(sb + 2 * 16384 + arow * 128 + cofs);
            kl_f[i] = *(const short8*)(sb + 3 * 16384 + arow * 128 + cofs);
            const int brow = wc * 64 + i * 16 + fr;  // l cols
            qh_f[i] = *(const short8*)(sb + 0 * 16384 + brow * 128 + cofs);
            ql_f[i] = *(const short8*)(sb + 1 * 16384 + brow * 128 + cofs);
        }
#pragma unroll
        for (int i = 0; i < 4; ++i)
#pragma unroll
            for (int j = 0; j < 4; ++j) {
                acc[i][j] = __builtin_amdgcn_mfma_f32_16x16x32_bf16(kh_f[i], qh_f[j], acc[i][j], 0, 0, 0);
                acc[i][j] = __builtin_amdgcn_mfma_f32_16x16x32_bf16(kh_f[i], ql_f[j], acc[i][j], 0, 0, 0);
                acc[i][j] = __builtin_amdgcn_mfma_f32_16x16x32_bf16(kl_f[i], qh_f[j], acc[i][j], 0, 0, 0);
            }
    }

    // ---- epilogue: l = l0+wc*64+j*16+fr (lane col), s = s0+wr*64+i*16+g*4+reg
    const float* invp = invden + (size_t)bh * NL + l0 + wc * 64 + fr;
#pragma unroll
    for (int j = 0; j < 4; ++j) {
        const float inv = invp[j * 16];
        float* orow = out + ((size_t)bh * NL + l0 + wc * 64 + j * 16 + fr) * NL + s0 + wr * 64 + g * 4;
#pragma unroll
        for (int i = 0; i < 4; ++i) {
            const f32x4 a = acc[i][j];
            float4 vv;
            vv.x = a[0] * inv; vv.y = a[1] * inv; vv.z = a[2] * inv; vv.w = a[3] * inv;
            *(float4*)(orow + i * 16) = vv;
        }
    }
}

extern "C" void kernel_launch(void* const* d_in, const int* in_sizes, int n_in,
                              void* d_out, int out_size, void* d_ws, size_t ws_size,
                              hipStream_t stream) {
    const float* query = (const float*)d_in[0];  // [B,L,H,D]
    const float* key   = (const float*)d_in[1];  // [B,L,H,D]
    const float* Wq    = (const float*)d_in[2];  // [H,D,D]
    const float* Wk    = (const float*)d_in[3];  // [H,D,D]
    float* out = (float*)d_out;                  // [B,H,L,S]

    const size_t npan = (size_t)NB * NH * NL * ND;  // 4.19M elems
    char* ws = (char*)d_ws;
    unsigned short* qbh = (unsigned short*)(ws);
    unsigned short* qbl = (unsigned short*)(ws + 1 * npan * 2);
    unsigned short* kbh = (unsigned short*)(ws + 2 * npan * 2);
    unsigned short* kbl = (unsigned short*)(ws + 3 * npan * 2);
    double* xsumk = (double*)(ws + 4 * npan * 2);
    double* v     = (double*)(ws + 4 * npan * 2 + 16384);
    float* invden = (float*)(ws + 4 * npan * 2 + 32768);

    proj_bf16_kernel<<<NB * NH * (NL / 128), 256, 0, stream>>>(query, Wq, qbh, qbl);
    proj_bf16_kernel<<<NB * NH * (NL / 128), 256, 0, stream>>>(key, Wk, kbh, kbl);
    xsum_kernel<<<NB * NH, 1024, 0, stream>>>(key, xsumk);
    prep_kernel<<<NB * NH, 64, 0, stream>>>(xsumk, Wq, Wk, v);
    den_kernel<<<dim3(NB * NH, NL / 256), 256, 0, stream>>>(query, v, invden);
    attn_kernel<<<dim3(NL / 128, NL / 128, NB * NH), 256, 0, stream>>>(qbh, qbl, kbh, kbl, invden, out);
}